// Round 10
// baseline (157.706 us; speedup 1.0000x reference)
//
#include <hip/hip_runtime.h>
#include <hip/hip_bf16.h>

typedef unsigned short u16;
typedef _Float16 f16;
typedef __attribute__((ext_vector_type(8))) _Float16 f16x8;
typedef __attribute__((ext_vector_type(2))) __fp16 h16x2;   // cvt_pkrtz return type
typedef __attribute__((ext_vector_type(8))) short short8;
typedef __attribute__((ext_vector_type(4))) float f32x4;

#define B_ 4
#define T_ 2048
#define D_ 512
#define H_ 8
#define M_ (B_*T_)          // 8192 rows
#define INV2PI 0.15915494309189535f

// ---- static device workspace ----
__device__ f16 g_qb[M_*D_];                // normalized q /2pi   8 MB
__device__ f16 g_kb[M_*D_];                // normalized k        8 MB
__device__ f16 g_kTp[(size_t)B_*H_*64*T_]; // k^T, slot-permuted  8 MB
__device__ f16 g_fA[(size_t)M_*D_];        // force half kh=0     8 MB
__device__ f16 g_fB[(size_t)M_*D_];        // force half kh=1     8 MB

__device__ inline float sin2pi(float x) {
#if __has_builtin(__builtin_amdgcn_sinf)
  return __builtin_amdgcn_sinf(x);   // v_sin_f32: sin(2*pi*x)
#else
  return __sinf(x * 6.283185307179586f);
#endif
}

// 16B global -> LDS direct (async DMA); dest = wave-uniform base + lane*16
__device__ inline void gload16(const void* g, void* l) {
  __builtin_amdgcn_global_load_lds(
      (const __attribute__((address_space(1))) unsigned int*)g,
      (__attribute__((address_space(3))) unsigned int*)l, 16, 0, 0);
}

// 8x fp32 -> fp16x8 via packed RTZ converts (1 instr per pair)
__device__ inline f16x8 cvt8h(f32x4 a, f32x4 b) {
  union { h16x2 h[4]; f16x8 v; } u;
  u.h[0] = __builtin_amdgcn_cvt_pkrtz(a[0], a[1]);
  u.h[1] = __builtin_amdgcn_cvt_pkrtz(a[2], a[3]);
  u.h[2] = __builtin_amdgcn_cvt_pkrtz(b[0], b[1]);
  u.h[3] = __builtin_amdgcn_cvt_pkrtz(b[2], b[3]);
  return u.v;
}

// slot permutation for the PV A-operand register layout:
// position p (0..31) in permuted storage holds original k = perm5(p)
__device__ inline int perm5(int p) {
  int lg = p >> 3, e = p & 7;
  return (e < 4) ? lg*4 + e : 16 + lg*4 + (e & 3);
}

// ---- GEMM C[m,n] = sum_k A[m,k]*Bt[n,k]  (K=512), fp16 MFMA ----
// 2D grid, x (m) fastest: consecutive blocks share the B-panel (L2-resident).
// MODE 0: z @ Wqk^T, epilogue = per-64-chunk l2-normalize -> g_qb (x 1/2pi) / g_kb
// MODE 1: (g_fA+g_fB) @ Wout^T + omega + b_out -> Cout fp32
template<int MODE>
__global__ __launch_bounds__(256, 2)
void gemm_bt(float* __restrict__ Cout, const float* __restrict__ add1,
             const float* __restrict__ add2, const float* __restrict__ Afp,
             const float* __restrict__ Bfp) {
  constexpr int K = 512;
  constexpr int N = (MODE == 0) ? 1024 : 512;
  __shared__ f16 As[128*72];
  __shared__ f16 Bs[128*72];
  const int m0 = blockIdx.x*128, n0 = blockIdx.y*128;
  const int t = threadIdx.x;
  const int w = t>>6, l = t&63;
  const int wr = (w>>1)*64, wc = (w&1)*64;
  const int lg = l>>4, li = l&15;
  const int srow = t>>3, scol = (t&7)*8;

  f32x4 acc[4][4] = {};

  for (int k0 = 0; k0 < K; k0 += 64) {
#pragma unroll
    for (int p = 0; p < 4; ++p) {
      int r = srow + p*32;
      {
        f32x4 b0 = *(const f32x4*)&Bfp[(size_t)(n0+r)*K + k0 + scol];
        f32x4 b1 = *(const f32x4*)&Bfp[(size_t)(n0+r)*K + k0 + scol + 4];
        *(f16x8*)&Bs[r*72 + scol] = cvt8h(b0, b1);
      }
      if (MODE == 0) {
        f32x4 a0 = *(const f32x4*)&Afp[(size_t)(m0+r)*K + k0 + scol];
        f32x4 a1 = *(const f32x4*)&Afp[(size_t)(m0+r)*K + k0 + scol + 4];
        *(f16x8*)&As[r*72 + scol] = cvt8h(a0, a1);
      } else {
        f16x8 a = *(const f16x8*)&g_fA[(size_t)(m0+r)*K + k0 + scol];
        f16x8 c = *(const f16x8*)&g_fB[(size_t)(m0+r)*K + k0 + scol];
        *(f16x8*)&As[r*72 + scol] = a + c;
      }
    }
    __syncthreads();
#pragma unroll
    for (int ks = 0; ks < 2; ++ks) {
      f16x8 af[4], bf[4];
#pragma unroll
      for (int i = 0; i < 4; ++i)
        af[i] = *(const f16x8*)&As[(wr + i*16 + li)*72 + ks*32 + lg*8];
#pragma unroll
      for (int j = 0; j < 4; ++j)
        bf[j] = *(const f16x8*)&Bs[(wc + j*16 + li)*72 + ks*32 + lg*8];
#pragma unroll
      for (int i = 0; i < 4; ++i)
#pragma unroll
        for (int j = 0; j < 4; ++j)
          acc[i][j] = __builtin_amdgcn_mfma_f32_16x16x32_f16(af[i], bf[j], acc[i][j], 0, 0, 0);
    }
    __syncthreads();
  }

  if (MODE == 0) {
    // fused per-head l2 normalize: each wave's 64-col tile is exactly one chunk
    const bool isq = (n0 < 512);
    f16* dst = isq ? g_qb : g_kb;
    const float qs = isq ? INV2PI : 1.0f;
    const int nb = (isq ? n0 : n0 - 512) + wc;
#pragma unroll
    for (int i = 0; i < 4; ++i) {
#pragma unroll
      for (int r = 0; r < 4; ++r) {
        float s = 0.f;
#pragma unroll
        for (int j = 0; j < 4; ++j) s += acc[i][j][r]*acc[i][j][r];
#pragma unroll
        for (int off = 1; off < 16; off <<= 1) s += __shfl_xor(s, off);
        float sc = qs / fmaxf(sqrtf(s), 1e-12f);
        int row = m0 + wr + i*16 + lg*4 + r;
#pragma unroll
        for (int j = 0; j < 4; ++j)
          dst[(size_t)row*D_ + nb + j*16 + li] = (f16)(acc[i][j][r]*sc);
      }
    }
  } else {
#pragma unroll
    for (int i = 0; i < 4; ++i) {
#pragma unroll
      for (int j = 0; j < 4; ++j) {
        int col = n0 + wc + j*16 + li;
        float badd = add1[col] + add2[col];
#pragma unroll
        for (int r = 0; r < 4; ++r) {
          int row = m0 + wr + i*16 + lg*4 + r;
          Cout[(size_t)row*N + col] = acc[i][j][r] + badd;
        }
      }
    }
  }
}

// ---- transpose k to [bh][d][t'] with PV slot permutation baked in ----
__global__ void transpose_k_kernel() {
  __shared__ u16 tile[64*72];
  const int t0 = blockIdx.x*64, bh = blockIdx.y;
  const int b = bh>>3, h = bh&7;
  const int t = threadIdx.x;
  const u16* kb = (const u16*)g_kb;
  u16* kT = (u16*)g_kTp;
  {
    int r = t>>2, cs = (t&3)*16;
    const u16* src = kb + (size_t)(b*T_ + t0 + r)*D_ + h*64 + cs;
    *(short8*)&tile[r*72 + cs]     = *(const short8*)(src);
    *(short8*)&tile[r*72 + cs + 8] = *(const short8*)(src + 8);
  }
  __syncthreads();
  {
    int d = t>>2, ts = (t&3)*16;
    short8 o0, o1;
#pragma unroll
    for (int j = 0; j < 8; ++j) {
      int p0 = ts + j, p1 = ts + 8 + j;
      int s0 = (p0 & ~31) | perm5(p0 & 31);
      int s1 = (p1 & ~31) | perm5(p1 & 31);
      o0[j] = (short)tile[s0*72 + d];
      o1[j] = (short)tile[s1*72 + d];
    }
    u16* dst = kT + ((size_t)bh*64 + d)*T_ + t0 + ts;
    *(short8*)(dst)     = o0;
    *(short8*)(dst + 8) = o1;
  }
}

// ---- fused  force = sin(Q K^T) K  per (b,h) ----
// 4 blocks/CU for cross-block MFMA/VALU pipe overlap (R9: 2 blocks/CU left
// both pipes at ~31% with identical totals -> pure-TLP fix). qt-tile 128,
// KVBLK 64, LDS 32KB/block, grid 1024. Same total MFMA/LDS/DMA work as R9.
// global_load_lds staging, both-sides XOR involution (conflict-free).
__global__ __launch_bounds__(256, 4)
void kuramoto_attn_kernel() {
  __shared__ f16 Ks[2][64*64];     // 8 KB each: [t 0..63][d slots 8x16B]
  __shared__ f16 KTs[2][64*64];    // 8 KB each: [d 0..63][t slots 8x16B]
  const int wg  = blockIdx.x;
  const int wgp = (wg & 7)*128 + (wg >> 3);  // XCD swizzle: 4 bh per XCD
  const int bh = wgp >> 5, qt = (wgp >> 1) & 15, kh = wgp & 1;
  const int b = bh >> 3, h = bh & 7;
  const int t = threadIdx.x;
  const int w = t>>6, l = t&63;
  const int lg = l>>4, li = l&15;

  // loop-invariant Q fragments (16 VGPR): wave w owns q rows w*32..w*32+31
  f16x8 bq[2][2];
#pragma unroll
  for (int ks = 0; ks < 2; ++ks)
#pragma unroll
    for (int j = 0; j < 2; ++j)
      bq[ks][j] = *(const f16x8*)&g_qb[(size_t)(b*T_ + qt*128 + w*32 + j*16 + li)*D_
                                       + h*64 + ks*32 + lg*8];

  const f16* kbase = g_kb  + (size_t)b*T_*D_ + h*64;
  const f16* tbase = g_kTp + (size_t)bh*64*T_;
  const int kt0 = kh*16;           // 16 kt-iters of 64 rows each

  // async stage of one 64-row kt tile:
  // Ks [64 t][8 slots], global slot = s ^ (t&7); KTs [64 d][8 slots], same XOR
#define STAGE(BUFI, KT) do {                                                   \
  _Pragma("unroll") for (int p = 0; p < 2; ++p) {                              \
    int idx = (w*2+p)*64 + l;                                                  \
    int rr = idx >> 3, ss = idx & 7;                                           \
    gload16(&kbase[(size_t)((KT)*64 + rr)*D_ + ((ss ^ (rr & 7))<<3)],          \
            &Ks[BUFI][(w*2+p)*512]);                                           \
    gload16(&tbase[(size_t)rr*T_ + (KT)*64 + ((ss ^ (rr & 7))<<3)],            \
            &KTs[BUFI][(w*2+p)*512]);                                          \
  } } while(0)

  f32x4 acc_o[2][4] = {};

  // prologue: stage kt0 into buffer 0 (barrier drains the DMA)
  STAGE(0, kt0);
  __syncthreads();

#define QK_STEP(KKP, S) do {                                                   \
  _Pragma("unroll") for (int ks = 0; ks < 2; ++ks) {                           \
    f16x8 af0 = *(const f16x8*)&Ks[buf][((2*(KKP)  )*16 + li)*64               \
                                        + (((ks*4+lg) ^ (li&7))<<3)];          \
    f16x8 af1 = *(const f16x8*)&Ks[buf][((2*(KKP)+1)*16 + li)*64               \
                                        + (((ks*4+lg) ^ (li&7))<<3)];          \
    __builtin_amdgcn_s_setprio(1);                                             \
    _Pragma("unroll") for (int j = 0; j < 2; ++j) {                            \
      S[0][j] = __builtin_amdgcn_mfma_f32_16x16x32_f16(af0, bq[ks][j], S[0][j], 0,0,0); \
      S[1][j] = __builtin_amdgcn_mfma_f32_16x16x32_f16(af1, bq[ks][j], S[1][j], 0,0,0); \
    }                                                                          \
    __builtin_amdgcn_s_setprio(0); } } while(0)

#define SINPV_STEP(KKP, S) do {                                                \
  f16x8 apv[2];                                                                \
  _Pragma("unroll") for (int j = 0; j < 2; ++j) {                              \
    union { h16x2 h[4]; f16x8 v; } cv;                                         \
    cv.h[0] = __builtin_amdgcn_cvt_pkrtz(sin2pi(S[0][j][0]), sin2pi(S[0][j][1])); \
    cv.h[1] = __builtin_amdgcn_cvt_pkrtz(sin2pi(S[0][j][2]), sin2pi(S[0][j][3])); \
    cv.h[2] = __builtin_amdgcn_cvt_pkrtz(sin2pi(S[1][j][0]), sin2pi(S[1][j][1])); \
    cv.h[3] = __builtin_amdgcn_cvt_pkrtz(sin2pi(S[1][j][2]), sin2pi(S[1][j][3])); \
    apv[j] = cv.v; }                                                           \
  _Pragma("unroll") for (int di = 0; di < 4; ++di) {                           \
    f16x8 bv = *(const f16x8*)&KTs[buf][(di*16 + li)*64                        \
                                        + ((((KKP)*4+lg) ^ (li&7))<<3)];       \
    __builtin_amdgcn_s_setprio(1);                                             \
    _Pragma("unroll") for (int j = 0; j < 2; ++j)                              \
      acc_o[j][di] = __builtin_amdgcn_mfma_f32_16x16x32_f16(apv[j], bv, acc_o[j][di], 0,0,0); \
    __builtin_amdgcn_s_setprio(0);                                             \
  } } while(0)

#pragma unroll 2
  for (int ii = 0; ii < 16; ++ii) {
    const int buf = ii & 1;
    // issue next-tile DMA first: in flight across the whole compute phase
    if (ii < 15) STAGE(buf^1, kt0 + ii + 1);

    // T15: both QK clusters issue before the sin/PV of the first
    f32x4 sA[2][2] = {};
    f32x4 sB[2][2] = {};
    QK_STEP(0, sA);
    QK_STEP(1, sB);
    SINPV_STEP(0, sA);
    SINPV_STEP(1, sB);

    __syncthreads();   // drains DMA (vmcnt) + protects both buffers
  }
#undef QK_STEP
#undef SINPV_STEP
#undef STAGE

  // write force half fp16 (row-major [b*T+t][h*64+d])
  f16* F = kh ? g_fB : g_fA;
#pragma unroll
  for (int j = 0; j < 2; ++j)
#pragma unroll
    for (int di = 0; di < 4; ++di)
#pragma unroll
      for (int r = 0; r < 4; ++r) {
        int row = b*T_ + qt*128 + w*32 + j*16 + lg*4 + r;
        int col = h*64 + di*16 + li;
        F[(size_t)row*D_ + col] = (f16)acc_o[j][di][r];
      }
}

extern "C" void kernel_launch(void* const* d_in, const int* in_sizes, int n_in,
                              void* d_out, int out_size, void* d_ws, size_t ws_size,
                              hipStream_t stream) {
  // inputs: t(unused), z, omega, W_qk, W_out, b_out  (all fp32)
  const float* z     = (const float*)d_in[1];
  const float* omega = (const float*)d_in[2];
  const float* Wqk   = (const float*)d_in[3];
  const float* Wout  = (const float*)d_in[4];
  const float* bout  = (const float*)d_in[5];
  float* out = (float*)d_out;

  gemm_bt<0><<<dim3(M_/128, 1024/128), 256, 0, stream>>>(nullptr, nullptr, nullptr, z, Wqk);
  transpose_k_kernel<<<dim3(T_/64, B_*H_), 256, 0, stream>>>();
  kuramoto_attn_kernel<<<1024, 256, 0, stream>>>();
  gemm_bt<1><<<dim3(M_/128, 512/128), 256, 0, stream>>>(out, omega, bout, nullptr, Wout);
}

// Round 11
// 149.166 us; speedup vs baseline: 1.0573x; 1.0573x over previous
//
#include <hip/hip_runtime.h>
#include <hip/hip_bf16.h>

typedef unsigned short u16;
typedef _Float16 f16;
typedef __attribute__((ext_vector_type(8))) _Float16 f16x8;
typedef __attribute__((ext_vector_type(4))) _Float16 f16x4;
typedef __attribute__((ext_vector_type(2))) __fp16 h16x2;   // cvt_pkrtz return type
typedef __attribute__((ext_vector_type(8))) short short8;
typedef __attribute__((ext_vector_type(4))) float f32x4;

#define B_ 4
#define T_ 2048
#define D_ 512
#define H_ 8
#define M_ (B_*T_)          // 8192 rows
#define INV2PI 0.15915494309189535f

// ---- static device workspace ----
__device__ f16 g_qb[M_*D_];                // normalized q /2pi   8 MB
__device__ f16 g_kb[M_*D_];                // normalized k        8 MB
__device__ f16 g_kTp[(size_t)B_*H_*64*T_]; // k^T, slot-permuted  8 MB
__device__ f16 g_fA[(size_t)M_*D_];        // force half kh=0     8 MB
__device__ f16 g_fB[(size_t)M_*D_];        // force half kh=1     8 MB

__device__ inline float sin2pi(float x) {
#if __has_builtin(__builtin_amdgcn_sinf)
  return __builtin_amdgcn_sinf(x);   // v_sin_f32: sin(2*pi*x)
#else
  return __sinf(x * 6.283185307179586f);
#endif
}

// 16B global -> LDS direct (async DMA); dest = wave-uniform base + lane*16
__device__ inline void gload16(const void* g, void* l) {
  __builtin_amdgcn_global_load_lds(
      (const __attribute__((address_space(1))) unsigned int*)g,
      (__attribute__((address_space(3))) unsigned int*)l, 16, 0, 0);
}

// 8x fp32 -> fp16x8 via packed RTZ converts (1 instr per pair)
__device__ inline f16x8 cvt8h(f32x4 a, f32x4 b) {
  union { h16x2 h[4]; f16x8 v; } u;
  u.h[0] = __builtin_amdgcn_cvt_pkrtz(a[0], a[1]);
  u.h[1] = __builtin_amdgcn_cvt_pkrtz(a[2], a[3]);
  u.h[2] = __builtin_amdgcn_cvt_pkrtz(b[0], b[1]);
  u.h[3] = __builtin_amdgcn_cvt_pkrtz(b[2], b[3]);
  return u.v;
}

// ---- GEMM C[m,n] = sum_k A[m,k]*Bt[n,k]  (K=512), fp16 MFMA ----
// 2D grid, x (m) fastest: consecutive blocks share the B-panel (L2-resident).
// MODE 0: z @ Wqk^T, epilogue = per-64-chunk l2-normalize -> g_qb (x 1/2pi) / g_kb;
//         k-half ALSO writes the transposed+inv-perm copy to g_kTp (fuses the
//         old transpose kernel; perm5 preserves aligned 4-runs -> 8B stores).
// MODE 1: (g_fA+g_fB) @ Wout^T + omega + b_out -> Cout fp32
template<int MODE>
__global__ __launch_bounds__(256, 2)
void gemm_bt(float* __restrict__ Cout, const float* __restrict__ add1,
             const float* __restrict__ add2, const float* __restrict__ Afp,
             const float* __restrict__ Bfp) {
  constexpr int K = 512;
  constexpr int N = (MODE == 0) ? 1024 : 512;
  __shared__ f16 As[128*72];
  __shared__ f16 Bs[128*72];
  const int m0 = blockIdx.x*128, n0 = blockIdx.y*128;
  const int t = threadIdx.x;
  const int w = t>>6, l = t&63;
  const int wr = (w>>1)*64, wc = (w&1)*64;
  const int lg = l>>4, li = l&15;
  const int srow = t>>3, scol = (t&7)*8;

  f32x4 acc[4][4] = {};

  for (int k0 = 0; k0 < K; k0 += 64) {
#pragma unroll
    for (int p = 0; p < 4; ++p) {
      int r = srow + p*32;
      {
        f32x4 b0 = *(const f32x4*)&Bfp[(size_t)(n0+r)*K + k0 + scol];
        f32x4 b1 = *(const f32x4*)&Bfp[(size_t)(n0+r)*K + k0 + scol + 4];
        *(f16x8*)&Bs[r*72 + scol] = cvt8h(b0, b1);
      }
      if (MODE == 0) {
        f32x4 a0 = *(const f32x4*)&Afp[(size_t)(m0+r)*K + k0 + scol];
        f32x4 a1 = *(const f32x4*)&Afp[(size_t)(m0+r)*K + k0 + scol + 4];
        *(f16x8*)&As[r*72 + scol] = cvt8h(a0, a1);
      } else {
        f16x8 a = *(const f16x8*)&g_fA[(size_t)(m0+r)*K + k0 + scol];
        f16x8 c = *(const f16x8*)&g_fB[(size_t)(m0+r)*K + k0 + scol];
        *(f16x8*)&As[r*72 + scol] = a + c;
      }
    }
    __syncthreads();
#pragma unroll
    for (int ks = 0; ks < 2; ++ks) {
      f16x8 af[4], bf[4];
#pragma unroll
      for (int i = 0; i < 4; ++i)
        af[i] = *(const f16x8*)&As[(wr + i*16 + li)*72 + ks*32 + lg*8];
#pragma unroll
      for (int j = 0; j < 4; ++j)
        bf[j] = *(const f16x8*)&Bs[(wc + j*16 + li)*72 + ks*32 + lg*8];
#pragma unroll
      for (int i = 0; i < 4; ++i)
#pragma unroll
        for (int j = 0; j < 4; ++j)
          acc[i][j] = __builtin_amdgcn_mfma_f32_16x16x32_f16(af[i], bf[j], acc[i][j], 0, 0, 0);
    }
    __syncthreads();
  }

  if (MODE == 0) {
    // fused per-head l2 normalize: each wave's 64-col tile is exactly one chunk
    const bool isq = (n0 < 512);
    f16* dst = isq ? g_qb : g_kb;
    const float qs = isq ? INV2PI : 1.0f;
    const int nb = (isq ? n0 : n0 - 512) + wc;
    f16 hv[4][4][4];   // [i][j][r] normalized values (k-half transposed store)
#pragma unroll
    for (int i = 0; i < 4; ++i) {
#pragma unroll
      for (int r = 0; r < 4; ++r) {
        float s = 0.f;
#pragma unroll
        for (int j = 0; j < 4; ++j) s += acc[i][j][r]*acc[i][j][r];
#pragma unroll
        for (int off = 1; off < 16; off <<= 1) s += __shfl_xor(s, off);
        float sc = qs / fmaxf(sqrtf(s), 1e-12f);
        int row = m0 + wr + i*16 + lg*4 + r;
#pragma unroll
        for (int j = 0; j < 4; ++j) {
          f16 v = (f16)(acc[i][j][r]*sc);
          hv[i][j][r] = v;
          dst[(size_t)row*D_ + nb + j*16 + li] = v;
        }
      }
    }
    if (!isq) {
      // transposed + inverse-perm5 write: g_kTp[(bh*64+d)*T + tpos]
      const int hh  = nb >> 6;             // head
      const int bh2 = (m0 >> 11)*H_ + hh;  // batch*8 + head
      const int t0b = (m0 & (T_-1)) + wr;  // within-batch t base of this wave
#pragma unroll
      for (int i = 0; i < 4; ++i) {
        int tloc = t0b + i*16 + lg*4;      // aligned 4-run start (r = 0..3)
        int g5 = tloc & ~31, k5 = tloc & 31;
        int p5 = (k5 < 16) ? ((k5>>2)*8) : (((k5-16)>>2)*8 + 4);
        int tpos = g5 + p5;
#pragma unroll
        for (int j = 0; j < 4; ++j) {
          f16x4 v4;
          v4[0]=hv[i][j][0]; v4[1]=hv[i][j][1]; v4[2]=hv[i][j][2]; v4[3]=hv[i][j][3];
          *(f16x4*)&g_kTp[((size_t)bh2*64 + j*16 + li)*T_ + tpos] = v4;
        }
      }
    }
  } else {
#pragma unroll
    for (int i = 0; i < 4; ++i) {
#pragma unroll
      for (int j = 0; j < 4; ++j) {
        int col = n0 + wc + j*16 + li;
        float badd = add1[col] + add2[col];
#pragma unroll
        for (int r = 0; r < 4; ++r) {
          int row = m0 + wr + i*16 + lg*4 + r;
          Cout[(size_t)row*N + col] = acc[i][j][r] + badd;
        }
      }
    }
  }
}

// ---- fused  force = sin(Q K^T) K  per (b,h) ----
// R9 structure (best measured: 42.7us, conflicts=0): grid 512, kt-split x2,
// 2 blocks/CU, 256-q tile, global_load_lds + both-sides XOR involution, T15
// 2-deep QK/sinPV interleave. setprio REMOVED this round: hypothesis is that
// prio-1 MFMA regions starve the co-resident block's sin-VALU phase and
// phase-lock the waves (m190's GEMM sign-flip) -> pipes serialize.
__global__ __launch_bounds__(256, 2)
void kuramoto_attn_kernel() {
  __shared__ f16 Ks[2][128*64];    // 16 KB each
  __shared__ f16 KTs[2][64*128];   // 16 KB each
  const int wg  = blockIdx.x;
  const int wgp = (wg & 7)*64 + (wg >> 3);   // XCD swizzle: 4 bh per XCD
  const int bh = wgp >> 4, qt = (wgp & 15) >> 1, kh = wgp & 1;
  const int b = bh >> 3, h = bh & 7;
  const int t = threadIdx.x;
  const int w = t>>6, l = t&63;
  const int lg = l>>4, li = l&15;

  // loop-invariant Q fragments (32 VGPR): wave w owns q rows w*64..w*64+63
  f16x8 bq[2][4];
#pragma unroll
  for (int ks = 0; ks < 2; ++ks)
#pragma unroll
    for (int j = 0; j < 4; ++j)
      bq[ks][j] = *(const f16x8*)&g_qb[(size_t)(b*T_ + qt*256 + w*64 + j*16 + li)*D_
                                       + h*64 + ks*32 + lg*8];

  const f16* kbase = g_kb  + (size_t)b*T_*D_ + h*64;
  const f16* tbase = g_kTp + (size_t)bh*64*T_;
  const int kt0 = kh*8;

  // async stage of one kt tile into buffer bufi:
  // Ks [128 rows][8 slots of 16B], global slot = s ^ (row&7)
  // KTs [64 rows][16 slots of 16B], global slot = s ^ (row&15)
#define STAGE(BUFI, KT) do {                                                   \
  _Pragma("unroll") for (int p = 0; p < 4; ++p) {                              \
    int idx = (w*4+p)*64 + l;                                                  \
    int rK = idx >> 3, sK = idx & 7;                                           \
    gload16(&kbase[(size_t)((KT)*128 + rK)*D_ + ((sK ^ (rK & 7))<<3)],         \
            &Ks[BUFI][(w*4+p)*512]);                                           \
    int rT = idx >> 4, sT = idx & 15;                                          \
    gload16(&tbase[(size_t)rT*T_ + (KT)*128 + ((sT ^ (rT & 15))<<3)],          \
            &KTs[BUFI][(w*4+p)*512]);                                          \
  } } while(0)

  f32x4 acc_o[4][4] = {};

  // prologue: stage kt0 into buffer 0 (barrier drains the DMA)
  STAGE(0, kt0);
  __syncthreads();

#define QK_STEP(KKP, S) do {                                                   \
  _Pragma("unroll") for (int ks = 0; ks < 2; ++ks) {                           \
    f16x8 af0 = *(const f16x8*)&Ks[buf][((2*(KKP)  )*16 + li)*64               \
                                        + (((ks*4+lg) ^ (li&7))<<3)];          \
    f16x8 af1 = *(const f16x8*)&Ks[buf][((2*(KKP)+1)*16 + li)*64               \
                                        + (((ks*4+lg) ^ (li&7))<<3)];          \
    _Pragma("unroll") for (int j = 0; j < 4; ++j) {                            \
      S[0][j] = __builtin_amdgcn_mfma_f32_16x16x32_f16(af0, bq[ks][j], S[0][j], 0,0,0); \
      S[1][j] = __builtin_amdgcn_mfma_f32_16x16x32_f16(af1, bq[ks][j], S[1][j], 0,0,0); \
    } } } while(0)

#define SINPV_STEP(KKP, S) do {                                                \
  f16x8 apv[4];                                                                \
  _Pragma("unroll") for (int j = 0; j < 4; ++j) {                              \
    union { h16x2 h[4]; f16x8 v; } cv;                                         \
    cv.h[0] = __builtin_amdgcn_cvt_pkrtz(sin2pi(S[0][j][0]), sin2pi(S[0][j][1])); \
    cv.h[1] = __builtin_amdgcn_cvt_pkrtz(sin2pi(S[0][j][2]), sin2pi(S[0][j][3])); \
    cv.h[2] = __builtin_amdgcn_cvt_pkrtz(sin2pi(S[1][j][0]), sin2pi(S[1][j][1])); \
    cv.h[3] = __builtin_amdgcn_cvt_pkrtz(sin2pi(S[1][j][2]), sin2pi(S[1][j][3])); \
    apv[j] = cv.v; }                                                           \
  _Pragma("unroll") for (int di = 0; di < 4; ++di) {                           \
    f16x8 bv = *(const f16x8*)&KTs[buf][(di*16 + li)*128                       \
                                        + ((((KKP)*4+lg) ^ li)<<3)];           \
    _Pragma("unroll") for (int j = 0; j < 4; ++j)                              \
      acc_o[j][di] = __builtin_amdgcn_mfma_f32_16x16x32_f16(apv[j], bv, acc_o[j][di], 0,0,0); \
  } } while(0)

#pragma unroll 2
  for (int ii = 0; ii < 8; ++ii) {
    const int buf = ii & 1;
    // issue next-tile DMA first: in flight across the whole compute phase
    if (ii < 7) STAGE(buf^1, kt0 + ii + 1);

    // 2-deep pipelined compute: QK[kkp+1] in flight while sin/PV[kkp] runs
    f32x4 sA[2][4] = {};
    f32x4 sB[2][4] = {};
    QK_STEP(0, sA);
    QK_STEP(1, sB);  SINPV_STEP(0, sA);
#pragma unroll
    for (int z = 0; z < 2; ++z)
#pragma unroll
      for (int j = 0; j < 4; ++j) sA[z][j] = (f32x4)(0.f);
    QK_STEP(2, sA);  SINPV_STEP(1, sB);
#pragma unroll
    for (int z = 0; z < 2; ++z)
#pragma unroll
      for (int j = 0; j < 4; ++j) sB[z][j] = (f32x4)(0.f);
    QK_STEP(3, sB);  SINPV_STEP(2, sA);
                     SINPV_STEP(3, sB);

    __syncthreads();   // drains DMA (vmcnt) + protects both buffers
  }
#undef QK_STEP
#undef SINPV_STEP
#undef STAGE

  // write force half fp16 (row-major [b*T+t][h*64+d])
  f16* F = kh ? g_fB : g_fA;
#pragma unroll
  for (int j = 0; j < 4; ++j)
#pragma unroll
    for (int di = 0; di < 4; ++di)
#pragma unroll
      for (int r = 0; r < 4; ++r) {
        int row = b*T_ + qt*256 + w*64 + j*16 + lg*4 + r;
        int col = h*64 + di*16 + li;
        F[(size_t)row*D_ + col] = (f16)acc_o[j][di][r];
      }
}

extern "C" void kernel_launch(void* const* d_in, const int* in_sizes, int n_in,
                              void* d_out, int out_size, void* d_ws, size_t ws_size,
                              hipStream_t stream) {
  // inputs: t(unused), z, omega, W_qk, W_out, b_out  (all fp32)
  const float* z     = (const float*)d_in[1];
  const float* omega = (const float*)d_in[2];
  const float* Wqk   = (const float*)d_in[3];
  const float* Wout  = (const float*)d_in[4];
  const float* bout  = (const float*)d_in[5];
  float* out = (float*)d_out;

  gemm_bt<0><<<dim3(M_/128, 1024/128), 256, 0, stream>>>(nullptr, nullptr, nullptr, z, Wqk);
  kuramoto_attn_kernel<<<512, 256, 0, stream>>>();
  gemm_bt<1><<<dim3(M_/128, 512/128), 256, 0, stream>>>(out, omega, bout, nullptr, Wout);
}